// Round 1
// baseline (518.621 us; speedup 1.0000x reference)
//
#include <hip/hip_runtime.h>

// GTConv: filt = softmax(weight, axis=0)  [R=8, C=4]
// out0 [2, R*E]: transpose(edge_index,(1,0,2)).reshape(2,R*E), written as float
// out1 [C, R*E]: vals[i, j*E+e] = filt[j,i] * edge_value[j,e]
// d_out = concat(out0.flat, out1.flat) as float32.

#define GT_E  2000000
#define GT_R  8
#define GT_C  4
#define GT_RE (GT_R * GT_E)   // 16,000,000

// ---- Kernel 1: permuted int->float copy of edge_index ----
// out element v in [0, 2*RE): s = v/RE, j = (v%RE)/E, e = v%E
// input element = j*(2E) + s*E + e   (edge_index laid out [R, 2, E])
__global__ __launch_bounds__(256) void gt_idx_kernel(const int* __restrict__ idx,
                                                     float* __restrict__ out) {
    long long t = (long long)blockIdx.x * 256 + threadIdx.x;
    long long v = t * 4;                       // 4 elements per thread
    if (v >= 2LL * GT_RE) return;
    int s   = (int)(v / GT_RE);
    int rem = (int)(v - (long long)s * GT_RE);
    int j   = rem / GT_E;
    int e   = rem - j * GT_E;
    long long in_off = (long long)j * (2 * GT_E) + (long long)s * GT_E + e;
    const int4 iv = *(const int4*)(idx + in_off);
    float4 f;
    f.x = (float)iv.x; f.y = (float)iv.y; f.z = (float)iv.z; f.w = (float)iv.w;
    *(float4*)(out + v) = f;
}

// ---- Kernel 2: vals = filt[j,i] * edge_value[j,e] ----
__global__ __launch_bounds__(256) void gt_vals_kernel(const float* __restrict__ w,
                                                      const float* __restrict__ ev,
                                                      float* __restrict__ out) {
    __shared__ float filt[GT_R * GT_C];
    if (threadIdx.x < GT_C) {
        int i = threadIdx.x;
        float col[GT_R];
        float m = -1e30f;
        #pragma unroll
        for (int j = 0; j < GT_R; ++j) { col[j] = w[j * GT_C + i]; m = fmaxf(m, col[j]); }
        float sum = 0.f;
        #pragma unroll
        for (int j = 0; j < GT_R; ++j) { col[j] = expf(col[j] - m); sum += col[j]; }
        float inv = 1.f / sum;
        #pragma unroll
        for (int j = 0; j < GT_R; ++j) filt[j * GT_C + i] = col[j] * inv;
    }
    __syncthreads();

    long long t = (long long)blockIdx.x * 256 + threadIdx.x;
    long long v = t * 4;                       // in [0, C*RE) = 64M
    if (v >= (long long)GT_C * GT_RE) return;
    int i   = (int)(v / GT_RE);
    int rem = (int)(v - (long long)i * GT_RE);
    int j   = rem / GT_E;
    int e   = rem - j * GT_E;
    const float4 x = *(const float4*)(ev + (long long)j * GT_E + e);
    float f = filt[j * GT_C + i];
    float4 r;
    r.x = x.x * f; r.y = x.y * f; r.z = x.z * f; r.w = x.w * f;
    *(float4*)(out + 2LL * GT_RE + v) = r;
}

extern "C" void kernel_launch(void* const* d_in, const int* in_sizes, int n_in,
                              void* d_out, int out_size, void* d_ws, size_t ws_size,
                              hipStream_t stream) {
    const float* weight     = (const float*)d_in[0];
    const int*   edge_index = (const int*)d_in[1];   // int inputs staged as int32
    const float* edge_value = (const float*)d_in[2];
    float* out = (float*)d_out;

    // out0: 32M elements / 4 per thread / 256 per block = 31250 blocks (exact)
    gt_idx_kernel<<<31250, 256, 0, stream>>>(edge_index, out);
    // out1: 64M elements / 4 per thread / 256 per block = 62500 blocks (exact)
    gt_vals_kernel<<<62500, 256, 0, stream>>>(weight, edge_value, out);
}